// Round 1
// baseline (5390.267 us; speedup 1.0000x reference)
//
#include <hip/hip_runtime.h>
#include <math.h>

// AttnBlock: GroupNorm -> q,k,v 1x1 conv -> full softmax attention over 4096
// positions -> 1x1 conv -> (x + h)/sqrt(2).
// Round 1: correctness-first fp32 implementation.
//   B=8, H=W=64 (N=4096), C=256, G=32.

namespace {
constexpr int Bn = 8;
constexpr int Np = 4096;                 // H*W
constexpr int Cc = 256;
constexpr float kEps = 1e-6f;
constexpr float kScale = 0.0625f;        // C^-0.5
constexpr float kRsqrt2 = 0.70710678118654752440f;
constexpr int kRows = Bn * Np;           // 32768
}  // namespace

// ---------------- GroupNorm ----------------
// One block per (b,g): reduce 4096*8 = 32768 elements.
__global__ __launch_bounds__(256) void gn_stats_k(const float* __restrict__ x,
                                                  float* __restrict__ st) {
  const int bg = blockIdx.x;
  const int b = bg >> 5, g = bg & 31;
  const float* base = x + (size_t)b * Np * Cc + g * 8;
  float s = 0.f, ss = 0.f;
  for (int i = threadIdx.x; i < Np * 2; i += 256) {
    const int p = i >> 1, hh = (i & 1) * 4;
    const float4 v = *(const float4*)(base + (size_t)p * Cc + hh);
    s += v.x + v.y + v.z + v.w;
    ss += v.x * v.x + v.y * v.y + v.z * v.z + v.w * v.w;
  }
  __shared__ float red[8];
#pragma unroll
  for (int off = 32; off; off >>= 1) {
    s += __shfl_down(s, off);
    ss += __shfl_down(ss, off);
  }
  const int wid = threadIdx.x >> 6;
  if ((threadIdx.x & 63) == 0) { red[wid] = s; red[wid + 4] = ss; }
  __syncthreads();
  if (threadIdx.x == 0) {
    s = red[0] + red[1] + red[2] + red[3];
    ss = red[4] + red[5] + red[6] + red[7];
    const float mean = s * (1.f / 32768.f);
    const float var = ss * (1.f / 32768.f) - mean * mean;
    st[bg * 2] = mean;
    st[bg * 2 + 1] = rsqrtf(var + kEps);
  }
}

__global__ __launch_bounds__(256) void gn_apply_k(const float* __restrict__ x,
                                                  const float* __restrict__ st,
                                                  const float* __restrict__ gs,
                                                  const float* __restrict__ gb,
                                                  float* __restrict__ h) {
  const int total = kRows * Cc / 4;  // float4 count
  for (int i = blockIdx.x * blockDim.x + threadIdx.x; i < total;
       i += gridDim.x * blockDim.x) {
    const int c4 = i & 63;          // C/4 = 64
    const int bp = i >> 6;
    const int b = bp >> 12;         // / 4096
    const int g = c4 >> 1;          // (c4*4)/8
    const float mean = st[(b * 32 + g) * 2];
    const float rstd = st[(b * 32 + g) * 2 + 1];
    const float4 xv = ((const float4*)x)[i];
    const float4 sv = ((const float4*)gs)[c4];
    const float4 bv = ((const float4*)gb)[c4];
    float4 o;
    o.x = (xv.x - mean) * rstd * sv.x + bv.x;
    o.y = (xv.y - mean) * rstd * sv.y + bv.y;
    o.z = (xv.z - mean) * rstd * sv.z + bv.z;
    o.w = (xv.w - mean) * rstd * sv.w + bv.w;
    ((float4*)h)[i] = o;
  }
}

// ---------------- fused QKV GEMM ----------------
// C_out[p][d] = sum_c h[p][c] * W[c][d] + b[d], for Wq/Wk/Wv sharing the A tile.
// 64x64 tile, 256 threads, 4x4 micro-tile per thread per output.
__global__ __launch_bounds__(256) void qkv_gemm_k(
    const float* __restrict__ h, const float* __restrict__ Wq,
    const float* __restrict__ bq, const float* __restrict__ Wk,
    const float* __restrict__ bk, const float* __restrict__ Wv,
    const float* __restrict__ bv, float* __restrict__ q, float* __restrict__ k,
    float* __restrict__ v) {
  __shared__ float As[16][68];
  __shared__ float Bq[16][68], Bk[16][68], Bv[16][68];
  const int m0 = blockIdx.x * 64;
  const int n0 = blockIdx.y * 64;
  const int t = threadIdx.x;
  const int tm = t >> 4, tn = t & 15;
  float aq[4][4] = {}, ak[4][4] = {}, av[4][4] = {};
  for (int k0 = 0; k0 < Cc; k0 += 16) {
    __syncthreads();
    {  // A tile: 64 rows x 16 k (transposed into [k][m])
      const int m = t >> 2, kk4 = (t & 3) * 4;
      const float4 a = *(const float4*)(h + (size_t)(m0 + m) * Cc + k0 + kk4);
      As[kk4 + 0][m] = a.x;
      As[kk4 + 1][m] = a.y;
      As[kk4 + 2][m] = a.z;
      As[kk4 + 3][m] = a.w;
    }
    {  // B tiles: 16 k x 64 n
      const int kk = t >> 4, n4 = (t & 15) * 4;
      const size_t off = (size_t)(k0 + kk) * Cc + n0 + n4;
      *(float4*)&Bq[kk][n4] = *(const float4*)(Wq + off);
      *(float4*)&Bk[kk][n4] = *(const float4*)(Wk + off);
      *(float4*)&Bv[kk][n4] = *(const float4*)(Wv + off);
    }
    __syncthreads();
#pragma unroll
    for (int kk = 0; kk < 16; ++kk) {
      const float4 a4 = *(const float4*)&As[kk][tm * 4];
      const float4 q4 = *(const float4*)&Bq[kk][tn * 4];
      const float4 k4 = *(const float4*)&Bk[kk][tn * 4];
      const float4 v4 = *(const float4*)&Bv[kk][tn * 4];
      const float a[4] = {a4.x, a4.y, a4.z, a4.w};
      const float qb[4] = {q4.x, q4.y, q4.z, q4.w};
      const float kb[4] = {k4.x, k4.y, k4.z, k4.w};
      const float vb[4] = {v4.x, v4.y, v4.z, v4.w};
#pragma unroll
      for (int i = 0; i < 4; ++i)
#pragma unroll
        for (int j = 0; j < 4; ++j) {
          aq[i][j] += a[i] * qb[j];
          ak[i][j] += a[i] * kb[j];
          av[i][j] += a[i] * vb[j];
        }
    }
  }
  const float4 qb4 = *(const float4*)(bq + n0 + tn * 4);
  const float4 kb4 = *(const float4*)(bk + n0 + tn * 4);
  const float4 vb4 = *(const float4*)(bv + n0 + tn * 4);
#pragma unroll
  for (int i = 0; i < 4; ++i) {
    const size_t r = (size_t)(m0 + tm * 4 + i) * Cc + n0 + tn * 4;
    float4 o;
    o.x = aq[i][0] + qb4.x; o.y = aq[i][1] + qb4.y;
    o.z = aq[i][2] + qb4.z; o.w = aq[i][3] + qb4.w;
    *(float4*)(q + r) = o;
    o.x = ak[i][0] + kb4.x; o.y = ak[i][1] + kb4.y;
    o.z = ak[i][2] + kb4.z; o.w = ak[i][3] + kb4.w;
    *(float4*)(k + r) = o;
    o.x = av[i][0] + vb4.x; o.y = av[i][1] + vb4.y;
    o.z = av[i][2] + vb4.z; o.w = av[i][3] + vb4.w;
    *(float4*)(v + r) = o;
  }
}

// ---------------- flash attention (fp32) ----------------
// Grid: (N/16, B). 16 queries per block, 16-key tiles, online softmax.
// Score phase: thread (qi, jj) = (t>>4, t&15) computes dot(q[qi], k[jj]).
// PV phase: channel-major, thread t owns channel c=t for all 16 queries.
__global__ __launch_bounds__(256) void attn_k(const float* __restrict__ q,
                                              const float* __restrict__ k,
                                              const float* __restrict__ v,
                                              float* __restrict__ o) {
  const int b = blockIdx.y;
  const int q0 = blockIdx.x * 16;
  __shared__ float qs[16][260], ks[16][260], vs[16][260];
  __shared__ float ps[16][20];
  __shared__ float rs[16], ls[16];
  const int t = threadIdx.x;
  const int qi = t >> 4, jj = t & 15;
  const float* qg = q + (size_t)b * Np * Cc;
  const float* kg = k + (size_t)b * Np * Cc;
  const float* vg = v + (size_t)b * Np * Cc;
#pragma unroll
  for (int rep = 0; rep < 4; ++rep) {
    const int idx = rep * 1024 + t * 4;
    const int row = idx >> 8, col = idx & 255;
    *(float4*)&qs[row][col] = *(const float4*)(qg + (size_t)(q0 + row) * Cc + col);
  }
  float m = -1e30f, l = 0.f;
  float acc[16] = {};
  for (int j0 = 0; j0 < Np; j0 += 16) {
    __syncthreads();  // prior tile's LDS reads complete
#pragma unroll
    for (int rep = 0; rep < 4; ++rep) {
      const int idx = rep * 1024 + t * 4;
      const int row = idx >> 8, col = idx & 255;
      *(float4*)&ks[row][col] =
          *(const float4*)(kg + (size_t)(j0 + row) * Cc + col);
      *(float4*)&vs[row][col] =
          *(const float4*)(vg + (size_t)(j0 + row) * Cc + col);
    }
    __syncthreads();
    // scores
    float s = 0.f;
#pragma unroll 8
    for (int c4 = 0; c4 < 64; ++c4) {
      const float4 a = *(const float4*)&qs[qi][c4 * 4];
      const float4 bb = *(const float4*)&ks[jj][c4 * 4];
      s += a.x * bb.x + a.y * bb.y + a.z * bb.z + a.w * bb.w;
    }
    s *= kScale;
    // online softmax within 16-lane row groups
    float mt = s;
#pragma unroll
    for (int off = 8; off; off >>= 1) mt = fmaxf(mt, __shfl_xor(mt, off));
    const float mn = fmaxf(m, mt);
    const float p = __expf(s - mn);
    float psum = p;
#pragma unroll
    for (int off = 8; off; off >>= 1) psum += __shfl_xor(psum, off);
    const float r = __expf(m - mn);
    l = l * r + psum;
    m = mn;
    ps[qi][jj] = p;
    if (jj == 0) rs[qi] = r;
    __syncthreads();
    // PV: channel-major
    float vr[16];
#pragma unroll
    for (int j = 0; j < 16; ++j) vr[j] = vs[j][t];
#pragma unroll
    for (int qq = 0; qq < 16; ++qq) {
      float a = acc[qq] * rs[qq];
#pragma unroll
      for (int j = 0; j < 16; ++j) a += ps[qq][j] * vr[j];
      acc[qq] = a;
    }
  }
  if (jj == 0) ls[qi] = l;
  __syncthreads();
#pragma unroll
  for (int qq = 0; qq < 16; ++qq) {
    o[(size_t)b * Np * Cc + (size_t)(q0 + qq) * Cc + t] = acc[qq] / ls[qq];
  }
}

// ---------------- final projection + residual ----------------
__global__ __launch_bounds__(256) void final_gemm_k(
    const float* __restrict__ h2, const float* __restrict__ Wf,
    const float* __restrict__ bf, const float* __restrict__ x,
    float* __restrict__ out) {
  __shared__ float As[16][68];
  __shared__ float Bs[16][68];
  const int m0 = blockIdx.x * 64;
  const int n0 = blockIdx.y * 64;
  const int t = threadIdx.x;
  const int tm = t >> 4, tn = t & 15;
  float ac[4][4] = {};
  for (int k0 = 0; k0 < Cc; k0 += 16) {
    __syncthreads();
    {
      const int m = t >> 2, kk4 = (t & 3) * 4;
      const float4 a = *(const float4*)(h2 + (size_t)(m0 + m) * Cc + k0 + kk4);
      As[kk4 + 0][m] = a.x;
      As[kk4 + 1][m] = a.y;
      As[kk4 + 2][m] = a.z;
      As[kk4 + 3][m] = a.w;
    }
    {
      const int kk = t >> 4, n4 = (t & 15) * 4;
      *(float4*)&Bs[kk][n4] = *(const float4*)(Wf + (size_t)(k0 + kk) * Cc + n0 + n4);
    }
    __syncthreads();
#pragma unroll
    for (int kk = 0; kk < 16; ++kk) {
      const float4 a4 = *(const float4*)&As[kk][tm * 4];
      const float4 b4 = *(const float4*)&Bs[kk][tn * 4];
      const float a[4] = {a4.x, a4.y, a4.z, a4.w};
      const float bb[4] = {b4.x, b4.y, b4.z, b4.w};
#pragma unroll
      for (int i = 0; i < 4; ++i)
#pragma unroll
        for (int j = 0; j < 4; ++j) ac[i][j] += a[i] * bb[j];
    }
  }
  const float4 bia = *(const float4*)(bf + n0 + tn * 4);
#pragma unroll
  for (int i = 0; i < 4; ++i) {
    const size_t r = (size_t)(m0 + tm * 4 + i) * Cc + n0 + tn * 4;
    const float4 xv = *(const float4*)(x + r);
    float4 oo;
    oo.x = (xv.x + ac[i][0] + bia.x) * kRsqrt2;
    oo.y = (xv.y + ac[i][1] + bia.y) * kRsqrt2;
    oo.z = (xv.z + ac[i][2] + bia.z) * kRsqrt2;
    oo.w = (xv.w + ac[i][3] + bia.w) * kRsqrt2;
    *(float4*)(out + r) = oo;
  }
}

extern "C" void kernel_launch(void* const* d_in, const int* in_sizes, int n_in,
                              void* d_out, int out_size, void* d_ws,
                              size_t ws_size, hipStream_t stream) {
  const float* x = (const float*)d_in[0];
  const float* gs = (const float*)d_in[1];
  const float* gb = (const float*)d_in[2];
  const float* Wq = (const float*)d_in[3];
  const float* bq = (const float*)d_in[4];
  const float* Wk = (const float*)d_in[5];
  const float* bk = (const float*)d_in[6];
  const float* Wv = (const float*)d_in[7];
  const float* bv = (const float*)d_in[8];
  const float* Wf = (const float*)d_in[9];
  const float* bf = (const float*)d_in[10];
  float* out = (float*)d_out;

  // workspace layout (floats): h | q | k | v | stats   (reuse h for attn out)
  float* h = (float*)d_ws;
  float* q = h + (size_t)kRows * Cc;
  float* k = q + (size_t)kRows * Cc;
  float* v = k + (size_t)kRows * Cc;
  float* st = v + (size_t)kRows * Cc;

  gn_stats_k<<<dim3(Bn * 32), dim3(256), 0, stream>>>(x, st);
  gn_apply_k<<<dim3(1024), dim3(256), 0, stream>>>(x, st, gs, gb, h);
  qkv_gemm_k<<<dim3(kRows / 64, Cc / 64), dim3(256), 0, stream>>>(
      h, Wq, bq, Wk, bk, Wv, bv, q, k, v);
  attn_k<<<dim3(Np / 16, Bn), dim3(256), 0, stream>>>(q, k, v, h);
  final_gemm_k<<<dim3(kRows / 64, Cc / 64), dim3(256), 0, stream>>>(h, Wf, bf,
                                                                    x, out);
}

// Round 2
// 700.378 us; speedup vs baseline: 7.6962x; 7.6962x over previous
//
#include <hip/hip_runtime.h>
#include <math.h>

// AttnBlock: GroupNorm -> q,k,v 1x1 conv -> full softmax attention over 4096
// positions -> 1x1 conv -> (x + h)/sqrt(2).
// Round 2: MFMA bf16 flash attention; QKV GEMM emits bf16 q,k and transposed
// bf16 V tiles. B=8, H=W=64 (N=4096), C=256, G=32.

typedef __attribute__((ext_vector_type(8))) short bf16x8;
typedef __attribute__((ext_vector_type(4))) float f32x4;
typedef unsigned short u16;

namespace {
constexpr int Bn = 8;
constexpr int Np = 4096;                 // H*W
constexpr int Cc = 256;
constexpr float kEps = 1e-6f;
constexpr float kScale = 0.0625f;        // C^-0.5 (folded into q)
constexpr float kRsqrt2 = 0.70710678118654752440f;
constexpr int kRows = Bn * Np;           // 32768
}  // namespace

__device__ __forceinline__ u16 f2b(float x) {
  unsigned int u = __float_as_uint(x);
  u += 0x7fffu + ((u >> 16) & 1u);       // round-to-nearest-even
  return (u16)(u >> 16);
}

// ---------------- GroupNorm ----------------
__global__ __launch_bounds__(256) void gn_stats_k(const float* __restrict__ x,
                                                  float* __restrict__ st) {
  const int bg = blockIdx.x;
  const int b = bg >> 5, g = bg & 31;
  const float* base = x + (size_t)b * Np * Cc + g * 8;
  float s = 0.f, ss = 0.f;
  for (int i = threadIdx.x; i < Np * 2; i += 256) {
    const int p = i >> 1, hh = (i & 1) * 4;
    const float4 v = *(const float4*)(base + (size_t)p * Cc + hh);
    s += v.x + v.y + v.z + v.w;
    ss += v.x * v.x + v.y * v.y + v.z * v.z + v.w * v.w;
  }
  __shared__ float red[8];
#pragma unroll
  for (int off = 32; off; off >>= 1) {
    s += __shfl_down(s, off);
    ss += __shfl_down(ss, off);
  }
  const int wid = threadIdx.x >> 6;
  if ((threadIdx.x & 63) == 0) { red[wid] = s; red[wid + 4] = ss; }
  __syncthreads();
  if (threadIdx.x == 0) {
    s = red[0] + red[1] + red[2] + red[3];
    ss = red[4] + red[5] + red[6] + red[7];
    const float mean = s * (1.f / 32768.f);
    const float var = ss * (1.f / 32768.f) - mean * mean;
    st[bg * 2] = mean;
    st[bg * 2 + 1] = rsqrtf(var + kEps);
  }
}

__global__ __launch_bounds__(256) void gn_apply_k(const float* __restrict__ x,
                                                  const float* __restrict__ st,
                                                  const float* __restrict__ gs,
                                                  const float* __restrict__ gb,
                                                  float* __restrict__ h) {
  const int total = kRows * Cc / 4;
  for (int i = blockIdx.x * blockDim.x + threadIdx.x; i < total;
       i += gridDim.x * blockDim.x) {
    const int c4 = i & 63;
    const int bp = i >> 6;
    const int b = bp >> 12;
    const int g = c4 >> 1;
    const float mean = st[(b * 32 + g) * 2];
    const float rstd = st[(b * 32 + g) * 2 + 1];
    const float4 xv = ((const float4*)x)[i];
    const float4 sv = ((const float4*)gs)[c4];
    const float4 bv = ((const float4*)gb)[c4];
    float4 o;
    o.x = (xv.x - mean) * rstd * sv.x + bv.x;
    o.y = (xv.y - mean) * rstd * sv.y + bv.y;
    o.z = (xv.z - mean) * rstd * sv.z + bv.z;
    o.w = (xv.w - mean) * rstd * sv.w + bv.w;
    ((float4*)h)[i] = o;
  }
}

// ---------------- fused QKV GEMM (fp32 compute, bf16 outputs) ----------------
// q: bf16 [n][c] pre-scaled by C^-0.5; k: bf16 [n][c];
// v: bf16 transposed tiles v_tt[b][n_tile][c][kv] (kv = position within tile).
__global__ __launch_bounds__(256) void qkv_gemm_k(
    const float* __restrict__ h, const float* __restrict__ Wq,
    const float* __restrict__ bq, const float* __restrict__ Wk,
    const float* __restrict__ bk, const float* __restrict__ Wv,
    const float* __restrict__ bv, u16* __restrict__ qg, u16* __restrict__ kg,
    u16* __restrict__ vtt) {
  __shared__ float As[16][68];
  __shared__ float Bq[16][68], Bk[16][68], Bv[16][68];
  __shared__ __align__(16) u16 vt[4096];  // 64 c x 64 kv, XOR-swizzled
  const int m0 = blockIdx.x * 64;
  const int n0 = blockIdx.y * 64;
  const int t = threadIdx.x;
  const int tm = t >> 4, tn = t & 15;
  float aq[4][4] = {}, ak[4][4] = {}, av[4][4] = {};
  for (int k0 = 0; k0 < Cc; k0 += 16) {
    __syncthreads();
    {
      const int m = t >> 2, kk4 = (t & 3) * 4;
      const float4 a = *(const float4*)(h + (size_t)(m0 + m) * Cc + k0 + kk4);
      As[kk4 + 0][m] = a.x;
      As[kk4 + 1][m] = a.y;
      As[kk4 + 2][m] = a.z;
      As[kk4 + 3][m] = a.w;
    }
    {
      const int kk = t >> 4, n4 = (t & 15) * 4;
      const size_t off = (size_t)(k0 + kk) * Cc + n0 + n4;
      *(float4*)&Bq[kk][n4] = *(const float4*)(Wq + off);
      *(float4*)&Bk[kk][n4] = *(const float4*)(Wk + off);
      *(float4*)&Bv[kk][n4] = *(const float4*)(Wv + off);
    }
    __syncthreads();
#pragma unroll
    for (int kk = 0; kk < 16; ++kk) {
      const float4 a4 = *(const float4*)&As[kk][tm * 4];
      const float4 q4 = *(const float4*)&Bq[kk][tn * 4];
      const float4 k4 = *(const float4*)&Bk[kk][tn * 4];
      const float4 v4 = *(const float4*)&Bv[kk][tn * 4];
      const float a[4] = {a4.x, a4.y, a4.z, a4.w};
      const float qb[4] = {q4.x, q4.y, q4.z, q4.w};
      const float kb[4] = {k4.x, k4.y, k4.z, k4.w};
      const float vb[4] = {v4.x, v4.y, v4.z, v4.w};
#pragma unroll
      for (int i = 0; i < 4; ++i)
#pragma unroll
        for (int j = 0; j < 4; ++j) {
          aq[i][j] += a[i] * qb[j];
          ak[i][j] += a[i] * kb[j];
          av[i][j] += a[i] * vb[j];
        }
    }
  }
  const float4 qb4 = *(const float4*)(bq + n0 + tn * 4);
  const float4 kb4 = *(const float4*)(bk + n0 + tn * 4);
  const float4 vb4 = *(const float4*)(bv + n0 + tn * 4);
  const float qbb[4] = {qb4.x, qb4.y, qb4.z, qb4.w};
  const float kbb[4] = {kb4.x, kb4.y, kb4.z, kb4.w};
  const float vbb[4] = {vb4.x, vb4.y, vb4.z, vb4.w};
  const int bb = m0 >> 12;            // batch
  const int jt = (m0 & 4095) >> 6;    // position tile within batch
#pragma unroll
  for (int i = 0; i < 4; ++i) {
    const size_t rbase = (size_t)(m0 + tm * 4 + i) * Cc + n0 + tn * 4;
    ushort4 qo, ko;
    qo.x = f2b((aq[i][0] + qbb[0]) * kScale);
    qo.y = f2b((aq[i][1] + qbb[1]) * kScale);
    qo.z = f2b((aq[i][2] + qbb[2]) * kScale);
    qo.w = f2b((aq[i][3] + qbb[3]) * kScale);
    ko.x = f2b(ak[i][0] + kbb[0]);
    ko.y = f2b(ak[i][1] + kbb[1]);
    ko.z = f2b(ak[i][2] + kbb[2]);
    ko.w = f2b(ak[i][3] + kbb[3]);
    *(ushort4*)(qg + rbase) = qo;
    *(ushort4*)(kg + rbase) = ko;
#pragma unroll
    for (int j = 0; j < 4; ++j) {
      const int n = tn * 4 + j;       // local channel
      const int m = tm * 4 + i;       // local kv
      const int byte = (n * 128 + m * 2) ^ ((n & 7) << 4);
      *(u16*)((char*)vt + byte) = f2b(av[i][j] + vbb[j]);
    }
  }
  __syncthreads();
#pragma unroll
  for (int i = 0; i < 2; ++i) {
    const int o = i * 256 + t;        // 512 chunks of 16B
    const int r = o >> 3, ch = o & 7;
    const int byte = (r * 128 + ch * 16) ^ ((r & 7) << 4);
    const uint4 val = *(const uint4*)((const char*)vt + byte);
    *(uint4*)(vtt + ((size_t)(bb * 64 + jt) * 256 + n0 + r) * 64 + ch * 8) = val;
  }
}

// ---------------- MFMA flash attention ----------------
// Grid (N/64, B), 256 threads (4 waves x 16 q-rows). KBLK=64.
// K LDS [64 key][256 ch], V^T LDS [256 ch][64 kv], both XOR-swizzled.
__global__ __launch_bounds__(256, 2) void attn_mfma_k(
    const u16* __restrict__ qg, const u16* __restrict__ kg,
    const u16* __restrict__ vtt, float* __restrict__ o) {
  __shared__ __align__(16) u16 Ks[64 * 256];
  __shared__ __align__(16) u16 Vs[256 * 64];
  __shared__ __align__(16) u16 Ps[4 * 16 * 64];
  const int b = blockIdx.y;
  const int q0 = blockIdx.x * 64;
  const int t = threadIdx.x;
  const int w = t >> 6, l = t & 63;
  const int lg = l >> 4, lr = l & 15;

  bf16x8 qf[8];
  {
    const u16* qrow = qg + ((size_t)b * Np + q0 + w * 16 + lr) * Cc;
#pragma unroll
    for (int s = 0; s < 8; ++s)
      qf[s] = *(const bf16x8*)(qrow + s * 32 + lg * 8);
  }
  f32x4 oacc[16];
#pragma unroll
  for (int n = 0; n < 16; ++n) oacc[n] = (f32x4){0.f, 0.f, 0.f, 0.f};
  float mrow[4] = {-1e30f, -1e30f, -1e30f, -1e30f};
  float lrow[4] = {0.f, 0.f, 0.f, 0.f};

  u16* Pw = Ps + w * 1024;
  const u16* kbase = kg + (size_t)b * Np * Cc;
  const u16* vbase = vtt + (size_t)b * 64 * 16384;

  for (int jt = 0; jt < 64; ++jt) {
    __syncthreads();  // all waves done reading previous K/V tile
    {
      const uint4* ksrc = (const uint4*)(kbase + (size_t)jt * 64 * Cc);
      const uint4* vsrc = (const uint4*)(vtt == nullptr ? nullptr
                                                        : vbase + (size_t)jt * 16384);
#pragma unroll
      for (int i = 0; i < 8; ++i) {
        const int cv = t + i * 256;
        const uint4 kvb = ksrc[cv];
        const int kb_ = (cv * 16) ^ (((cv >> 5) & 7) << 4);  // 512B rows
        *(uint4*)((char*)Ks + kb_) = kvb;
        const uint4 vvb = vsrc[cv];
        const int vb_ = (cv * 16) ^ (((cv >> 3) & 7) << 4);  // 128B rows
        *(uint4*)((char*)Vs + vb_) = vvb;
      }
    }
    __syncthreads();

    // ---- scores S = q . k  (q pre-scaled) ----
    f32x4 sacc[4];
#pragma unroll
    for (int t4 = 0; t4 < 4; ++t4) sacc[t4] = (f32x4){0.f, 0.f, 0.f, 0.f};
#pragma unroll
    for (int s = 0; s < 8; ++s) {
#pragma unroll
      for (int t4 = 0; t4 < 4; ++t4) {
        const int key = t4 * 16 + lr;
        const int off = (key * 512 + s * 64 + lg * 16) ^ ((lr & 7) << 4);
        const bf16x8 kf = *(const bf16x8*)((const char*)Ks + off);
        sacc[t4] =
            __builtin_amdgcn_mfma_f32_16x16x32_bf16(qf[s], kf, sacc[t4], 0, 0, 0);
      }
    }
    // ---- online softmax: lane owns rows lg*4+r, cols t4*16+lr ----
    float fr[4];
#pragma unroll
    for (int r = 0; r < 4; ++r) {
      float mt = fmaxf(fmaxf(sacc[0][r], sacc[1][r]),
                       fmaxf(sacc[2][r], sacc[3][r]));
#pragma unroll
      for (int off = 1; off < 16; off <<= 1) mt = fmaxf(mt, __shfl_xor(mt, off));
      const float mn = fmaxf(mrow[r], mt);
      fr[r] = __expf(mrow[r] - mn);
      mrow[r] = mn;
      float ps = 0.f;
      const int row = lg * 4 + r;
#pragma unroll
      for (int t4 = 0; t4 < 4; ++t4) {
        const float p = __expf(sacc[t4][r] - mn);
        ps += p;
        const int byte = (row * 128 + (t4 * 16 + lr) * 2) ^ ((row & 7) << 4);
        *(u16*)((char*)Pw + byte) = f2b(p);
      }
#pragma unroll
      for (int off = 1; off < 16; off <<= 1) ps += __shfl_xor(ps, off);
      lrow[r] = lrow[r] * fr[r] + ps;
    }
#pragma unroll
    for (int n = 0; n < 16; ++n)
#pragma unroll
      for (int r = 0; r < 4; ++r) oacc[n][r] *= fr[r];
    // ---- PV ----
#pragma unroll
    for (int s2 = 0; s2 < 2; ++s2) {
      const int pb = (lr * 128 + s2 * 64 + lg * 16) ^ ((lr & 7) << 4);
      const bf16x8 pf = *(const bf16x8*)((const char*)Pw + pb);
#pragma unroll
      for (int n = 0; n < 16; ++n) {
        const int c = n * 16 + lr;
        const int vo = (c * 128 + s2 * 64 + lg * 16) ^ ((lr & 7) << 4);
        const bf16x8 vf = *(const bf16x8*)((const char*)Vs + vo);
        oacc[n] =
            __builtin_amdgcn_mfma_f32_16x16x32_bf16(pf, vf, oacc[n], 0, 0, 0);
      }
    }
  }
  // ---- epilogue: divide by softmax denom, store fp32 ----
  float inv[4];
#pragma unroll
  for (int r = 0; r < 4; ++r) inv[r] = 1.f / lrow[r];
  float* orow = o + ((size_t)b * Np + q0 + w * 16 + lg * 4) * Cc;
#pragma unroll
  for (int r = 0; r < 4; ++r)
#pragma unroll
    for (int n = 0; n < 16; ++n)
      orow[(size_t)r * Cc + n * 16 + lr] = oacc[n][r] * inv[r];
}

// ---------------- final projection + residual ----------------
__global__ __launch_bounds__(256) void final_gemm_k(
    const float* __restrict__ h2, const float* __restrict__ Wf,
    const float* __restrict__ bf, const float* __restrict__ x,
    float* __restrict__ out) {
  __shared__ float As[16][68];
  __shared__ float Bs[16][68];
  const int m0 = blockIdx.x * 64;
  const int n0 = blockIdx.y * 64;
  const int t = threadIdx.x;
  const int tm = t >> 4, tn = t & 15;
  float ac[4][4] = {};
  for (int k0 = 0; k0 < Cc; k0 += 16) {
    __syncthreads();
    {
      const int m = t >> 2, kk4 = (t & 3) * 4;
      const float4 a = *(const float4*)(h2 + (size_t)(m0 + m) * Cc + k0 + kk4);
      As[kk4 + 0][m] = a.x;
      As[kk4 + 1][m] = a.y;
      As[kk4 + 2][m] = a.z;
      As[kk4 + 3][m] = a.w;
    }
    {
      const int kk = t >> 4, n4 = (t & 15) * 4;
      *(float4*)&Bs[kk][n4] =
          *(const float4*)(Wf + (size_t)(k0 + kk) * Cc + n0 + n4);
    }
    __syncthreads();
#pragma unroll
    for (int kk = 0; kk < 16; ++kk) {
      const float4 a4 = *(const float4*)&As[kk][tm * 4];
      const float4 b4 = *(const float4*)&Bs[kk][tn * 4];
      const float a[4] = {a4.x, a4.y, a4.z, a4.w};
      const float bb[4] = {b4.x, b4.y, b4.z, b4.w};
#pragma unroll
      for (int i = 0; i < 4; ++i)
#pragma unroll
        for (int j = 0; j < 4; ++j) ac[i][j] += a[i] * bb[j];
    }
  }
  const float4 bia = *(const float4*)(bf + n0 + tn * 4);
#pragma unroll
  for (int i = 0; i < 4; ++i) {
    const size_t r = (size_t)(m0 + tm * 4 + i) * Cc + n0 + tn * 4;
    const float4 xv = *(const float4*)(x + r);
    float4 oo;
    oo.x = (xv.x + ac[i][0] + bia.x) * kRsqrt2;
    oo.y = (xv.y + ac[i][1] + bia.y) * kRsqrt2;
    oo.z = (xv.z + ac[i][2] + bia.z) * kRsqrt2;
    oo.w = (xv.w + ac[i][3] + bia.w) * kRsqrt2;
    *(float4*)(out + r) = oo;
  }
}

extern "C" void kernel_launch(void* const* d_in, const int* in_sizes, int n_in,
                              void* d_out, int out_size, void* d_ws,
                              size_t ws_size, hipStream_t stream) {
  const float* x = (const float*)d_in[0];
  const float* gs = (const float*)d_in[1];
  const float* gb = (const float*)d_in[2];
  const float* Wq = (const float*)d_in[3];
  const float* bq = (const float*)d_in[4];
  const float* Wk = (const float*)d_in[5];
  const float* bk = (const float*)d_in[6];
  const float* Wv = (const float*)d_in[7];
  const float* bv = (const float*)d_in[8];
  const float* Wf = (const float*)d_in[9];
  const float* bf = (const float*)d_in[10];
  float* out = (float*)d_out;

  // workspace: h fp32 (reused for attn out) | q bf16 | k bf16 | v_tt bf16 | st
  float* h = (float*)d_ws;
  u16* qb = (u16*)(h + (size_t)kRows * Cc);
  u16* kb = qb + (size_t)kRows * Cc;
  u16* vtt = kb + (size_t)kRows * Cc;
  float* st = (float*)(vtt + (size_t)kRows * Cc);

  gn_stats_k<<<dim3(Bn * 32), dim3(256), 0, stream>>>(x, st);
  gn_apply_k<<<dim3(1024), dim3(256), 0, stream>>>(x, st, gs, gb, h);
  qkv_gemm_k<<<dim3(kRows / 64, Cc / 64), dim3(256), 0, stream>>>(
      h, Wq, bq, Wk, bk, Wv, bv, qb, kb, vtt);
  attn_mfma_k<<<dim3(Np / 64, Bn), dim3(256), 0, stream>>>(qb, kb, vtt, h);
  final_gemm_k<<<dim3(kRows / 64, Cc / 64), dim3(256), 0, stream>>>(h, Wf, bf,
                                                                    x, out);
}

// Round 3
// 542.803 us; speedup vs baseline: 9.9304x; 1.2903x over previous
//
#include <hip/hip_runtime.h>
#include <math.h>

// AttnBlock: GroupNorm -> q,k,v 1x1 conv -> full softmax attention over 4096
// positions -> 1x1 conv -> (x + h)/sqrt(2).
// Round 3: pipelined MFMA flash attention. QBLK=128 (8 waves), K/V double-
// buffered in LDS via global_load_lds from PRE-SWIZZLED global tiles
// (qkv_gemm stores K and V^T already XOR-swizzled; attention copies tiles
// linearly, reads with the same XOR). Batch<->XCD pinned block mapping.
// B=8, H=W=64 (N=4096), C=256, G=32.

typedef __attribute__((ext_vector_type(8))) short bf16x8;
typedef __attribute__((ext_vector_type(4))) float f32x4;
typedef unsigned short u16;
typedef __attribute__((address_space(3))) unsigned int lds_u32;
typedef __attribute__((address_space(1))) unsigned int glb_u32;

namespace {
constexpr int Bn = 8;
constexpr int Np = 4096;                 // H*W
constexpr int Cc = 256;
constexpr float kEps = 1e-6f;
constexpr float kScale = 0.0625f;        // C^-0.5 (folded into q)
constexpr float kRsqrt2 = 0.70710678118654752440f;
constexpr int kRows = Bn * Np;           // 32768
}  // namespace

__device__ __forceinline__ u16 f2b(float x) {
  unsigned int u = __float_as_uint(x);
  u += 0x7fffu + ((u >> 16) & 1u);       // round-to-nearest-even
  return (u16)(u >> 16);
}

__device__ __forceinline__ void stage16(const void* g, void* l) {
  __builtin_amdgcn_global_load_lds((const glb_u32*)g, (lds_u32*)l, 16, 0, 0);
}

// ---------------- GroupNorm ----------------
__global__ __launch_bounds__(256) void gn_stats_k(const float* __restrict__ x,
                                                  float* __restrict__ st) {
  const int bg = blockIdx.x;
  const int b = bg >> 5, g = bg & 31;
  const float* base = x + (size_t)b * Np * Cc + g * 8;
  float s = 0.f, ss = 0.f;
  for (int i = threadIdx.x; i < Np * 2; i += 256) {
    const int p = i >> 1, hh = (i & 1) * 4;
    const float4 v = *(const float4*)(base + (size_t)p * Cc + hh);
    s += v.x + v.y + v.z + v.w;
    ss += v.x * v.x + v.y * v.y + v.z * v.z + v.w * v.w;
  }
  __shared__ float red[8];
#pragma unroll
  for (int off = 32; off; off >>= 1) {
    s += __shfl_down(s, off);
    ss += __shfl_down(ss, off);
  }
  const int wid = threadIdx.x >> 6;
  if ((threadIdx.x & 63) == 0) { red[wid] = s; red[wid + 4] = ss; }
  __syncthreads();
  if (threadIdx.x == 0) {
    s = red[0] + red[1] + red[2] + red[3];
    ss = red[4] + red[5] + red[6] + red[7];
    const float mean = s * (1.f / 32768.f);
    const float var = ss * (1.f / 32768.f) - mean * mean;
    st[bg * 2] = mean;
    st[bg * 2 + 1] = rsqrtf(var + kEps);
  }
}

__global__ __launch_bounds__(256) void gn_apply_k(const float* __restrict__ x,
                                                  const float* __restrict__ st,
                                                  const float* __restrict__ gs,
                                                  const float* __restrict__ gb,
                                                  float* __restrict__ h) {
  const int total = kRows * Cc / 4;
  for (int i = blockIdx.x * blockDim.x + threadIdx.x; i < total;
       i += gridDim.x * blockDim.x) {
    const int c4 = i & 63;
    const int bp = i >> 6;
    const int b = bp >> 12;
    const int g = c4 >> 1;
    const float mean = st[(b * 32 + g) * 2];
    const float rstd = st[(b * 32 + g) * 2 + 1];
    const float4 xv = ((const float4*)x)[i];
    const float4 sv = ((const float4*)gs)[c4];
    const float4 bv = ((const float4*)gb)[c4];
    float4 o;
    o.x = (xv.x - mean) * rstd * sv.x + bv.x;
    o.y = (xv.y - mean) * rstd * sv.y + bv.y;
    o.z = (xv.z - mean) * rstd * sv.z + bv.z;
    o.w = (xv.w - mean) * rstd * sv.w + bv.w;
    ((float4*)h)[i] = o;
  }
}

// ---------------- fused QKV GEMM (fp32 compute, bf16 outputs) ----------------
// q: bf16 [n][c] pre-scaled by C^-0.5.
// k: bf16 SWIZZLED 32KB tiles per 64 rows: byte = (key*512 + ch*2)^((key&7)<<4).
// v: bf16 SWIZZLED transposed tiles [row/64][ch][kv]:
//    byte-in-tile = (ch*128 + kv*2)^((ch&7)<<4).
__global__ __launch_bounds__(256) void qkv_gemm_k(
    const float* __restrict__ h, const float* __restrict__ Wq,
    const float* __restrict__ bq, const float* __restrict__ Wk,
    const float* __restrict__ bk, const float* __restrict__ Wv,
    const float* __restrict__ bv, u16* __restrict__ qg, u16* __restrict__ kg,
    u16* __restrict__ vtt) {
  __shared__ float As[16][68];
  __shared__ float Bq[16][68], Bk[16][68], Bv[16][68];
  __shared__ __align__(16) u16 vt[4096];  // 64 ch x 64 kv, XOR-swizzled
  const int m0 = blockIdx.x * 64;
  const int n0 = blockIdx.y * 64;
  const int t = threadIdx.x;
  const int tm = t >> 4, tn = t & 15;
  float aq[4][4] = {}, ak[4][4] = {}, av[4][4] = {};
  for (int k0 = 0; k0 < Cc; k0 += 16) {
    __syncthreads();
    {
      const int m = t >> 2, kk4 = (t & 3) * 4;
      const float4 a = *(const float4*)(h + (size_t)(m0 + m) * Cc + k0 + kk4);
      As[kk4 + 0][m] = a.x;
      As[kk4 + 1][m] = a.y;
      As[kk4 + 2][m] = a.z;
      As[kk4 + 3][m] = a.w;
    }
    {
      const int kk = t >> 4, n4 = (t & 15) * 4;
      const size_t off = (size_t)(k0 + kk) * Cc + n0 + n4;
      *(float4*)&Bq[kk][n4] = *(const float4*)(Wq + off);
      *(float4*)&Bk[kk][n4] = *(const float4*)(Wk + off);
      *(float4*)&Bv[kk][n4] = *(const float4*)(Wv + off);
    }
    __syncthreads();
#pragma unroll
    for (int kk = 0; kk < 16; ++kk) {
      const float4 a4 = *(const float4*)&As[kk][tm * 4];
      const float4 q4 = *(const float4*)&Bq[kk][tn * 4];
      const float4 k4 = *(const float4*)&Bk[kk][tn * 4];
      const float4 v4 = *(const float4*)&Bv[kk][tn * 4];
      const float a[4] = {a4.x, a4.y, a4.z, a4.w};
      const float qb[4] = {q4.x, q4.y, q4.z, q4.w};
      const float kb[4] = {k4.x, k4.y, k4.z, k4.w};
      const float vb[4] = {v4.x, v4.y, v4.z, v4.w};
#pragma unroll
      for (int i = 0; i < 4; ++i)
#pragma unroll
        for (int j = 0; j < 4; ++j) {
          aq[i][j] += a[i] * qb[j];
          ak[i][j] += a[i] * kb[j];
          av[i][j] += a[i] * vb[j];
        }
    }
  }
  const float4 qb4 = *(const float4*)(bq + n0 + tn * 4);
  const float4 kb4 = *(const float4*)(bk + n0 + tn * 4);
  const float4 vb4 = *(const float4*)(bv + n0 + tn * 4);
  const float qbb[4] = {qb4.x, qb4.y, qb4.z, qb4.w};
  const float kbb[4] = {kb4.x, kb4.y, kb4.z, kb4.w};
  const float vbb[4] = {vb4.x, vb4.y, vb4.z, vb4.w};
  char* ktile = (char*)kg + ((size_t)(m0 >> 6)) * 32768;
#pragma unroll
  for (int i = 0; i < 4; ++i) {
    const size_t rbase = (size_t)(m0 + tm * 4 + i) * Cc + n0 + tn * 4;
    ushort4 qo, ko;
    qo.x = f2b((aq[i][0] + qbb[0]) * kScale);
    qo.y = f2b((aq[i][1] + qbb[1]) * kScale);
    qo.z = f2b((aq[i][2] + qbb[2]) * kScale);
    qo.w = f2b((aq[i][3] + qbb[3]) * kScale);
    ko.x = f2b(ak[i][0] + kbb[0]);
    ko.y = f2b(ak[i][1] + kbb[1]);
    ko.z = f2b(ak[i][2] + kbb[2]);
    ko.w = f2b(ak[i][3] + kbb[3]);
    *(ushort4*)(qg + rbase) = qo;
    {  // swizzled K tile write (8B chunk; XOR only touches bits 4-6)
      const int key = tm * 4 + i;  // 0..63 within tile (m0 is 64-aligned)
      const int kbyte = (key * 512 + (n0 + tn * 4) * 2) ^ ((key & 7) << 4);
      *(ushort4*)(ktile + kbyte) = ko;
    }
#pragma unroll
    for (int j = 0; j < 4; ++j) {
      const int n = tn * 4 + j;       // local channel
      const int m = tm * 4 + i;       // local kv
      const int byte = (n * 128 + m * 2) ^ ((n & 7) << 4);
      *(u16*)((char*)vt + byte) = f2b(av[i][j] + vbb[j]);
    }
  }
  __syncthreads();
  // linear copy of the (already swizzled) 8KB ch-slice into the global tile
  char* vtile = (char*)vtt + ((size_t)(m0 >> 6)) * 32768 + (size_t)n0 * 128;
#pragma unroll
  for (int i = 0; i < 2; ++i) {
    const int o = i * 256 + t;        // 512 chunks of 16B
    *(uint4*)(vtile + o * 16) = *(const uint4*)((const char*)vt + o * 16);
  }
}

// ---------------- pipelined MFMA flash attention ----------------
// Grid: 256 blocks, 512 threads (8 waves x 16 q-rows = QBLK 128). KBLK=64.
// block id i -> batch = i&7 (pins batch to XCD under round-robin dispatch),
// q-tile = i>>3. K tile [64 key][256 ch] and V^T tile [256 ch][64 kv] arrive
// pre-swizzled from global via global_load_lds (linear copy), double-buffered.
__global__ __launch_bounds__(512, 2) void attn_mfma_k(
    const u16* __restrict__ qg, const u16* __restrict__ ksw,
    const u16* __restrict__ vsw, float* __restrict__ o) {
  __shared__ __align__(16) u16 Ks[2][64 * 256];   // 2 x 32KB
  __shared__ __align__(16) u16 Vs[2][256 * 64];   // 2 x 32KB
  __shared__ __align__(16) u16 Ps[8][1024];       // 8 waves x 2KB
  const int id = blockIdx.x;
  const int b = id & 7;
  const int q0 = (id >> 3) * 128;
  const int t = threadIdx.x;
  const int w = t >> 6, l = t & 63;
  const int lg = l >> 4, lr = l & 15;

  const char* kbase = (const char*)ksw + (size_t)b * Np * Cc * 2;
  const char* vbase = (const char*)vsw + (size_t)b * Np * Cc * 2;

  bf16x8 qf[8];
  {
    const u16* qrow = qg + ((size_t)b * Np + q0 + w * 16 + lr) * Cc;
#pragma unroll
    for (int s = 0; s < 8; ++s)
      qf[s] = *(const bf16x8*)(qrow + s * 32 + lg * 8);
  }
  f32x4 oacc[16];
#pragma unroll
  for (int n = 0; n < 16; ++n) oacc[n] = (f32x4){0.f, 0.f, 0.f, 0.f};
  float mrow[4] = {-1e30f, -1e30f, -1e30f, -1e30f};
  float lrow[4] = {0.f, 0.f, 0.f, 0.f};

  char* Pw = (char*)&Ps[w][0];

  // stage tile jt into buffer nxt: each wave copies 4KB of K + 4KB of V
  auto stage = [&](int jt, int nxt) {
    const char* kt = kbase + (size_t)jt * 32768;
    const char* vtb = vbase + (size_t)jt * 32768;
    char* kd = (char*)&Ks[nxt][0];
    char* vd = (char*)&Vs[nxt][0];
#pragma unroll
    for (int c2 = 0; c2 < 4; ++c2) {
      const int chunk = w * 4 + c2;
      stage16(kt + chunk * 1024 + l * 16, kd + chunk * 1024);
      stage16(vtb + chunk * 1024 + l * 16, vd + chunk * 1024);
    }
  };

  stage(0, 0);
  __syncthreads();  // drains vmcnt: tile 0 resident

  for (int jt = 0; jt < 64; ++jt) {
    const int cur = jt & 1;
    if (jt + 1 < 64) stage(jt + 1, cur ^ 1);  // prefetch BEFORE compute

    // ---- scores S = q . k  (q pre-scaled) ----
    f32x4 sacc[4];
#pragma unroll
    for (int t4 = 0; t4 < 4; ++t4) sacc[t4] = (f32x4){0.f, 0.f, 0.f, 0.f};
    const char* Kc = (const char*)&Ks[cur][0];
#pragma unroll
    for (int s = 0; s < 8; ++s) {
#pragma unroll
      for (int t4 = 0; t4 < 4; ++t4) {
        const int key = t4 * 16 + lr;
        const int off = (key * 512 + s * 64 + lg * 16) ^ ((lr & 7) << 4);
        const bf16x8 kf = *(const bf16x8*)(Kc + off);
        sacc[t4] =
            __builtin_amdgcn_mfma_f32_16x16x32_bf16(qf[s], kf, sacc[t4], 0, 0, 0);
      }
    }
    // ---- online softmax: lane owns rows lg*4+r, cols t4*16+lr ----
    float fr[4];
#pragma unroll
    for (int r = 0; r < 4; ++r) {
      float mt = fmaxf(fmaxf(sacc[0][r], sacc[1][r]),
                       fmaxf(sacc[2][r], sacc[3][r]));
#pragma unroll
      for (int off = 1; off < 16; off <<= 1) mt = fmaxf(mt, __shfl_xor(mt, off));
      const float mn = fmaxf(mrow[r], mt);
      fr[r] = __expf(mrow[r] - mn);
      mrow[r] = mn;
      float ps = 0.f;
      const int row = lg * 4 + r;
      const int sw = (row & 12) << 3;
#pragma unroll
      for (int t4 = 0; t4 < 4; ++t4) {
        const float p = __expf(sacc[t4][r] - mn);
        ps += p;
        const int byte = (row * 128 + (t4 * 16 + lr) * 2) ^ sw;
        *(u16*)(Pw + byte) = f2b(p);
      }
#pragma unroll
      for (int off = 1; off < 16; off <<= 1) ps += __shfl_xor(ps, off);
      lrow[r] = lrow[r] * fr[r] + ps;
    }
#pragma unroll
    for (int n = 0; n < 16; ++n)
#pragma unroll
      for (int r = 0; r < 4; ++r) oacc[n][r] *= fr[r];
    // ---- PV ----
    const char* Vc = (const char*)&Vs[cur][0];
#pragma unroll
    for (int s2 = 0; s2 < 2; ++s2) {
      const int pb = (lr * 128 + s2 * 64 + lg * 16) ^ ((lr & 12) << 3);
      const bf16x8 pf = *(const bf16x8*)(Pw + pb);
#pragma unroll
      for (int n = 0; n < 16; ++n) {
        const int c = n * 16 + lr;
        const int vo = (c * 128 + s2 * 64 + lg * 16) ^ ((lr & 7) << 4);
        const bf16x8 vf = *(const bf16x8*)(Vc + vo);
        oacc[n] =
            __builtin_amdgcn_mfma_f32_16x16x32_bf16(pf, vf, oacc[n], 0, 0, 0);
      }
    }
    __syncthreads();  // drains vmcnt (prefetch done) + all waves done with cur
  }
  // ---- epilogue: divide by softmax denom, store fp32 ----
  float inv[4];
#pragma unroll
  for (int r = 0; r < 4; ++r) inv[r] = 1.f / lrow[r];
  float* orow = o + ((size_t)b * Np + q0 + w * 16 + lg * 4) * Cc;
#pragma unroll
  for (int r = 0; r < 4; ++r)
#pragma unroll
    for (int n = 0; n < 16; ++n)
      orow[(size_t)r * Cc + n * 16 + lr] = oacc[n][r] * inv[r];
}

// ---------------- final projection + residual ----------------
__global__ __launch_bounds__(256) void final_gemm_k(
    const float* __restrict__ h2, const float* __restrict__ Wf,
    const float* __restrict__ bf, const float* __restrict__ x,
    float* __restrict__ out) {
  __shared__ float As[16][68];
  __shared__ float Bs[16][68];
  const int m0 = blockIdx.x * 64;
  const int n0 = blockIdx.y * 64;
  const int t = threadIdx.x;
  const int tm = t >> 4, tn = t & 15;
  float ac[4][4] = {};
  for (int k0 = 0; k0 < Cc; k0 += 16) {
    __syncthreads();
    {
      const int m = t >> 2, kk4 = (t & 3) * 4;
      const float4 a = *(const float4*)(h2 + (size_t)(m0 + m) * Cc + k0 + kk4);
      As[kk4 + 0][m] = a.x;
      As[kk4 + 1][m] = a.y;
      As[kk4 + 2][m] = a.z;
      As[kk4 + 3][m] = a.w;
    }
    {
      const int kk = t >> 4, n4 = (t & 15) * 4;
      *(float4*)&Bs[kk][n4] =
          *(const float4*)(Wf + (size_t)(k0 + kk) * Cc + n0 + n4);
    }
    __syncthreads();
#pragma unroll
    for (int kk = 0; kk < 16; ++kk) {
      const float4 a4 = *(const float4*)&As[kk][tm * 4];
      const float4 b4 = *(const float4*)&Bs[kk][tn * 4];
      const float a[4] = {a4.x, a4.y, a4.z, a4.w};
      const float bb[4] = {b4.x, b4.y, b4.z, b4.w};
#pragma unroll
      for (int i = 0; i < 4; ++i)
#pragma unroll
        for (int j = 0; j < 4; ++j) ac[i][j] += a[i] * bb[j];
    }
  }
  const float4 bia = *(const float4*)(bf + n0 + tn * 4);
#pragma unroll
  for (int i = 0; i < 4; ++i) {
    const size_t r = (size_t)(m0 + tm * 4 + i) * Cc + n0 + tn * 4;
    const float4 xv = *(const float4*)(x + r);
    float4 oo;
    oo.x = (xv.x + ac[i][0] + bia.x) * kRsqrt2;
    oo.y = (xv.y + ac[i][1] + bia.y) * kRsqrt2;
    oo.z = (xv.z + ac[i][2] + bia.z) * kRsqrt2;
    oo.w = (xv.w + ac[i][3] + bia.w) * kRsqrt2;
    *(float4*)(out + r) = oo;
  }
}

extern "C" void kernel_launch(void* const* d_in, const int* in_sizes, int n_in,
                              void* d_out, int out_size, void* d_ws,
                              size_t ws_size, hipStream_t stream) {
  const float* x = (const float*)d_in[0];
  const float* gs = (const float*)d_in[1];
  const float* gb = (const float*)d_in[2];
  const float* Wq = (const float*)d_in[3];
  const float* bq = (const float*)d_in[4];
  const float* Wk = (const float*)d_in[5];
  const float* bk = (const float*)d_in[6];
  const float* Wv = (const float*)d_in[7];
  const float* bv = (const float*)d_in[8];
  const float* Wf = (const float*)d_in[9];
  const float* bf = (const float*)d_in[10];
  float* out = (float*)d_out;

  // workspace: h fp32 (reused for attn out) | q bf16 | k_sw bf16 | v_sw bf16 | st
  float* h = (float*)d_ws;
  u16* qb = (u16*)(h + (size_t)kRows * Cc);
  u16* kb = qb + (size_t)kRows * Cc;
  u16* vtt = kb + (size_t)kRows * Cc;
  float* st = (float*)(vtt + (size_t)kRows * Cc);

  gn_stats_k<<<dim3(Bn * 32), dim3(256), 0, stream>>>(x, st);
  gn_apply_k<<<dim3(1024), dim3(256), 0, stream>>>(x, st, gs, gb, h);
  qkv_gemm_k<<<dim3(kRows / 64, Cc / 64), dim3(256), 0, stream>>>(
      h, Wq, bq, Wk, bk, Wv, bv, qb, kb, vtt);
  attn_mfma_k<<<dim3(256), dim3(512), 0, stream>>>(qb, kb, vtt, h);
  final_gemm_k<<<dim3(kRows / 64, Cc / 64), dim3(256), 0, stream>>>(h, Wf, bf,
                                                                    x, out);
}

// Round 4
// 447.244 us; speedup vs baseline: 12.0522x; 1.2137x over previous
//
#include <hip/hip_runtime.h>
#include <math.h>

// AttnBlock: GroupNorm -> q,k,v 1x1 conv -> full softmax attention over 4096
// positions -> 1x1 conv -> (x + h)/sqrt(2).
// Round 4: attention rewritten around 32x32x16 MFMA with swapped QK^T
// (S^T = K*Q^T) so softmax is lane-local, P kept in registers via
// v_cvt_pk_bf16_f32 + half-wave exchange (no P LDS), 32 q-rows/wave,
// 4 waves/block, defer-max rescale. K/V double-buffered via global_load_lds
// from pre-swizzled global tiles. B=8, H=W=64 (N=4096), C=256, G=32.

typedef __attribute__((ext_vector_type(8))) short bf16x8;
typedef __attribute__((ext_vector_type(4))) float f32x4;
typedef __attribute__((ext_vector_type(16))) float f32x16;
typedef unsigned short u16;
typedef __attribute__((address_space(3))) unsigned int lds_u32;
typedef __attribute__((address_space(1))) unsigned int glb_u32;

namespace {
constexpr int Bn = 8;
constexpr int Np = 4096;                 // H*W
constexpr int Cc = 256;
constexpr float kEps = 1e-6f;
constexpr float kScale = 0.0625f;        // C^-0.5 (folded into q)
constexpr float kRsqrt2 = 0.70710678118654752440f;
constexpr int kRows = Bn * Np;           // 32768
}  // namespace

__device__ __forceinline__ u16 f2b(float x) {
  unsigned int u = __float_as_uint(x);
  u += 0x7fffu + ((u >> 16) & 1u);       // round-to-nearest-even
  return (u16)(u >> 16);
}

__device__ __forceinline__ unsigned int cvtpk(float lo, float hi) {
  unsigned int r;
  asm volatile("v_cvt_pk_bf16_f32 %0, %1, %2" : "=v"(r) : "v"(lo), "v"(hi));
  return r;
}

__device__ __forceinline__ void stage16(const void* g, void* l) {
  __builtin_amdgcn_global_load_lds((const glb_u32*)g, (lds_u32*)l, 16, 0, 0);
}

// ---------------- GroupNorm ----------------
__global__ __launch_bounds__(256) void gn_stats_k(const float* __restrict__ x,
                                                  float* __restrict__ st) {
  const int bg = blockIdx.x;
  const int b = bg >> 5, g = bg & 31;
  const float* base = x + (size_t)b * Np * Cc + g * 8;
  float s = 0.f, ss = 0.f;
  for (int i = threadIdx.x; i < Np * 2; i += 256) {
    const int p = i >> 1, hh = (i & 1) * 4;
    const float4 v = *(const float4*)(base + (size_t)p * Cc + hh);
    s += v.x + v.y + v.z + v.w;
    ss += v.x * v.x + v.y * v.y + v.z * v.z + v.w * v.w;
  }
  __shared__ float red[8];
#pragma unroll
  for (int off = 32; off; off >>= 1) {
    s += __shfl_down(s, off);
    ss += __shfl_down(ss, off);
  }
  const int wid = threadIdx.x >> 6;
  if ((threadIdx.x & 63) == 0) { red[wid] = s; red[wid + 4] = ss; }
  __syncthreads();
  if (threadIdx.x == 0) {
    s = red[0] + red[1] + red[2] + red[3];
    ss = red[4] + red[5] + red[6] + red[7];
    const float mean = s * (1.f / 32768.f);
    const float var = ss * (1.f / 32768.f) - mean * mean;
    st[bg * 2] = mean;
    st[bg * 2 + 1] = rsqrtf(var + kEps);
  }
}

__global__ __launch_bounds__(256) void gn_apply_k(const float* __restrict__ x,
                                                  const float* __restrict__ st,
                                                  const float* __restrict__ gs,
                                                  const float* __restrict__ gb,
                                                  float* __restrict__ h) {
  const int total = kRows * Cc / 4;
  for (int i = blockIdx.x * blockDim.x + threadIdx.x; i < total;
       i += gridDim.x * blockDim.x) {
    const int c4 = i & 63;
    const int bp = i >> 6;
    const int b = bp >> 12;
    const int g = c4 >> 1;
    const float mean = st[(b * 32 + g) * 2];
    const float rstd = st[(b * 32 + g) * 2 + 1];
    const float4 xv = ((const float4*)x)[i];
    const float4 sv = ((const float4*)gs)[c4];
    const float4 bv = ((const float4*)gb)[c4];
    float4 o;
    o.x = (xv.x - mean) * rstd * sv.x + bv.x;
    o.y = (xv.y - mean) * rstd * sv.y + bv.y;
    o.z = (xv.z - mean) * rstd * sv.z + bv.z;
    o.w = (xv.w - mean) * rstd * sv.w + bv.w;
    ((float4*)h)[i] = o;
  }
}

// ---------------- fused QKV GEMM (fp32 compute, bf16 outputs) ----------------
// q: bf16 [n][c] pre-scaled by C^-0.5.
// k: bf16 SWIZZLED 32KB tiles per 64 rows: byte = (key*512 + ch*2)^((key&7)<<4).
// v: bf16 SWIZZLED transposed tiles [row/64][ch][kv]:
//    byte-in-tile = (ch*128 + kv*2)^((ch&7)<<4).
__global__ __launch_bounds__(256) void qkv_gemm_k(
    const float* __restrict__ h, const float* __restrict__ Wq,
    const float* __restrict__ bq, const float* __restrict__ Wk,
    const float* __restrict__ bk, const float* __restrict__ Wv,
    const float* __restrict__ bv, u16* __restrict__ qg, u16* __restrict__ kg,
    u16* __restrict__ vtt) {
  __shared__ float As[16][68];
  __shared__ float Bq[16][68], Bk[16][68], Bv[16][68];
  __shared__ __align__(16) u16 vt[4096];  // 64 ch x 64 kv, XOR-swizzled
  const int m0 = blockIdx.x * 64;
  const int n0 = blockIdx.y * 64;
  const int t = threadIdx.x;
  const int tm = t >> 4, tn = t & 15;
  float aq[4][4] = {}, ak[4][4] = {}, av[4][4] = {};
  for (int k0 = 0; k0 < Cc; k0 += 16) {
    __syncthreads();
    {
      const int m = t >> 2, kk4 = (t & 3) * 4;
      const float4 a = *(const float4*)(h + (size_t)(m0 + m) * Cc + k0 + kk4);
      As[kk4 + 0][m] = a.x;
      As[kk4 + 1][m] = a.y;
      As[kk4 + 2][m] = a.z;
      As[kk4 + 3][m] = a.w;
    }
    {
      const int kk = t >> 4, n4 = (t & 15) * 4;
      const size_t off = (size_t)(k0 + kk) * Cc + n0 + n4;
      *(float4*)&Bq[kk][n4] = *(const float4*)(Wq + off);
      *(float4*)&Bk[kk][n4] = *(const float4*)(Wk + off);
      *(float4*)&Bv[kk][n4] = *(const float4*)(Wv + off);
    }
    __syncthreads();
#pragma unroll
    for (int kk = 0; kk < 16; ++kk) {
      const float4 a4 = *(const float4*)&As[kk][tm * 4];
      const float4 q4 = *(const float4*)&Bq[kk][tn * 4];
      const float4 k4 = *(const float4*)&Bk[kk][tn * 4];
      const float4 v4 = *(const float4*)&Bv[kk][tn * 4];
      const float a[4] = {a4.x, a4.y, a4.z, a4.w};
      const float qb[4] = {q4.x, q4.y, q4.z, q4.w};
      const float kb[4] = {k4.x, k4.y, k4.z, k4.w};
      const float vb[4] = {v4.x, v4.y, v4.z, v4.w};
#pragma unroll
      for (int i = 0; i < 4; ++i)
#pragma unroll
        for (int j = 0; j < 4; ++j) {
          aq[i][j] += a[i] * qb[j];
          ak[i][j] += a[i] * kb[j];
          av[i][j] += a[i] * vb[j];
        }
    }
  }
  const float4 qb4 = *(const float4*)(bq + n0 + tn * 4);
  const float4 kb4 = *(const float4*)(bk + n0 + tn * 4);
  const float4 vb4 = *(const float4*)(bv + n0 + tn * 4);
  const float qbb[4] = {qb4.x, qb4.y, qb4.z, qb4.w};
  const float kbb[4] = {kb4.x, kb4.y, kb4.z, kb4.w};
  const float vbb[4] = {vb4.x, vb4.y, vb4.z, vb4.w};
  char* ktile = (char*)kg + ((size_t)(m0 >> 6)) * 32768;
#pragma unroll
  for (int i = 0; i < 4; ++i) {
    const size_t rbase = (size_t)(m0 + tm * 4 + i) * Cc + n0 + tn * 4;
    ushort4 qo, ko;
    qo.x = f2b((aq[i][0] + qbb[0]) * kScale);
    qo.y = f2b((aq[i][1] + qbb[1]) * kScale);
    qo.z = f2b((aq[i][2] + qbb[2]) * kScale);
    qo.w = f2b((aq[i][3] + qbb[3]) * kScale);
    ko.x = f2b(ak[i][0] + kbb[0]);
    ko.y = f2b(ak[i][1] + kbb[1]);
    ko.z = f2b(ak[i][2] + kbb[2]);
    ko.w = f2b(ak[i][3] + kbb[3]);
    *(ushort4*)(qg + rbase) = qo;
    {  // swizzled K tile write (8B chunk; XOR only touches bits 4-6)
      const int key = tm * 4 + i;  // 0..63 within tile (m0 is 64-aligned)
      const int kbyte = (key * 512 + (n0 + tn * 4) * 2) ^ ((key & 7) << 4);
      *(ushort4*)(ktile + kbyte) = ko;
    }
#pragma unroll
    for (int j = 0; j < 4; ++j) {
      const int n = tn * 4 + j;       // local channel
      const int m = tm * 4 + i;       // local kv
      const int byte = (n * 128 + m * 2) ^ ((n & 7) << 4);
      *(u16*)((char*)vt + byte) = f2b(av[i][j] + vbb[j]);
    }
  }
  __syncthreads();
  // linear copy of the (already swizzled) 8KB ch-slice into the global tile
  char* vtile = (char*)vtt + ((size_t)(m0 >> 6)) * 32768 + (size_t)n0 * 128;
#pragma unroll
  for (int i = 0; i < 2; ++i) {
    const int o = i * 256 + t;        // 512 chunks of 16B
    *(uint4*)(vtile + o * 16) = *(const uint4*)((const char*)vt + o * 16);
  }
}

// ---------------- MFMA flash attention, 32x32 fragments ----------------
// Grid: 256 blocks, 256 threads (4 waves x 32 q-rows = QBLK 128). KBLK=64.
// block id i -> batch = i&7 (pins batch to XCD), q-tile = i>>3.
// S^T = K*Q^T via mfma(A=K_frag, B=Q_frag): lane owns one q-column
// (col = l&31), 16 keys (rows (r&3)+8*(r>>2)+4*hi) -> softmax is lane-local
// + one shfl_xor(32). P converted to bf16 PV B-fragments in registers.
// PV: O^T[d][q] = V^T * P^T via mfma(A=V^T_frag, B=P_frag).
__global__ __launch_bounds__(256, 1) void attn_mfma_k(
    const u16* __restrict__ qg, const u16* __restrict__ ksw,
    const u16* __restrict__ vsw, float* __restrict__ o) {
  __shared__ __align__(16) u16 Ks[2][64 * 256];   // 2 x 32KB
  __shared__ __align__(16) u16 Vs[2][256 * 64];   // 2 x 32KB
  const int id = blockIdx.x;
  const int b = id & 7;
  const int q0 = (id >> 3) * 128;
  const int t = threadIdx.x;
  const int w = t >> 6, l = t & 63;
  const int lq = l & 31;   // q-column / key-row / channel-row lane index
  const int hi = l >> 5;   // k-slice half

  const char* kbase = (const char*)ksw + (size_t)b * Np * Cc * 2;
  const char* vbase = (const char*)vsw + (size_t)b * Np * Cc * 2;

  // Q fragments (B-operand of QK^T): qf[ks] = Q[q0+w*32+lq][ks*16+hi*8 ..+7]
  bf16x8 qf[16];
  {
    const u16* qrow = qg + ((size_t)b * Np + q0 + w * 32 + lq) * Cc;
#pragma unroll
    for (int ks = 0; ks < 16; ++ks)
      qf[ks] = *(const bf16x8*)(qrow + ks * 16 + hi * 8);
  }
  f32x16 oacc[8];
#pragma unroll
  for (int nb = 0; nb < 8; ++nb)
#pragma unroll
    for (int r = 0; r < 16; ++r) oacc[nb][r] = 0.f;
  float mrow = -1e30f, lrow = 0.f;

  auto stage = [&](int jt, int nxt) {
    const char* kt = kbase + (size_t)jt * 32768;
    const char* vt = vbase + (size_t)jt * 32768;
    char* kd = (char*)&Ks[nxt][0];
    char* vd = (char*)&Vs[nxt][0];
#pragma unroll
    for (int i = 0; i < 8; ++i) {
      const int c = i * 256 + t;
      stage16(kt + c * 16, kd + c * 16);
      stage16(vt + c * 16, vd + c * 16);
    }
  };

  stage(0, 0);
  __syncthreads();  // drains vmcnt: tile 0 resident

  for (int jt = 0; jt < 64; ++jt) {
    const int cur = jt & 1;
    if (jt + 1 < 64) stage(jt + 1, cur ^ 1);  // prefetch BEFORE compute

    const char* Kc = (const char*)&Ks[cur][0];
    const char* Vc = (const char*)&Vs[cur][0];

    // ---- S^T[key][q]: two 32-key row blocks ----
    f32x16 sacc[2];
#pragma unroll
    for (int kb = 0; kb < 2; ++kb)
#pragma unroll
      for (int r = 0; r < 16; ++r) sacc[kb][r] = 0.f;
#pragma unroll
    for (int ks = 0; ks < 16; ++ks) {
#pragma unroll
      for (int kb = 0; kb < 2; ++kb) {
        const int key = kb * 32 + lq;
        const int off = (key * 512 + ks * 32 + hi * 16) ^ ((key & 7) << 4);
        const bf16x8 kf = *(const bf16x8*)(Kc + off);
        sacc[kb] = __builtin_amdgcn_mfma_f32_32x32x16_bf16(kf, qf[ks],
                                                           sacc[kb], 0, 0, 0);
      }
    }
    // ---- online softmax: lane owns 32 scores of column q ----
    float m8[8];
#pragma unroll
    for (int i = 0; i < 8; ++i)
      m8[i] = fmaxf(fmaxf(sacc[0][i], sacc[0][i + 8]),
                    fmaxf(sacc[1][i], sacc[1][i + 8]));
    float mt = fmaxf(fmaxf(fmaxf(m8[0], m8[1]), fmaxf(m8[2], m8[3])),
                     fmaxf(fmaxf(m8[4], m8[5]), fmaxf(m8[6], m8[7])));
    mt = fmaxf(mt, __shfl_xor(mt, 32));
    if (!__all(mt <= mrow + 8.f)) {   // defer-max: rescale only on real growth
      const float mn = fmaxf(mrow, mt);
      const float fr = __expf(mrow - mn);
      mrow = mn;
      lrow *= fr;
#pragma unroll
      for (int nb = 0; nb < 8; ++nb)
#pragma unroll
        for (int r = 0; r < 16; ++r) oacc[nb][r] *= fr;
    }
    float ps = 0.f;
#pragma unroll
    for (int kb = 0; kb < 2; ++kb)
#pragma unroll
      for (int r = 0; r < 16; ++r) {
        const float p = __expf(sacc[kb][r] - mrow);
        sacc[kb][r] = p;
        ps += p;
      }
    ps += __shfl_xor(ps, 32);
    lrow += ps;
    // ---- P^T -> bf16 PV B-fragments (registers only) ----
    // sacc[kb][r] holds P^T[key = kb*32 + (r&3)+8*(r>>2)+4*hi][q=lq].
    // B-frag for k-step ks needs keys ks*16 + hi*8 + e; source reg
    // r = (e&3) + 8*(ks&1) + 4*hi from lane half hi' = e>>2.
    unsigned int Wp[2][8], Xp[2][8];
#pragma unroll
    for (int kb = 0; kb < 2; ++kb)
#pragma unroll
      for (int m = 0; m < 8; ++m) {
        Wp[kb][m] = cvtpk(sacc[kb][2 * m], sacc[kb][2 * m + 1]);
        Xp[kb][m] = (unsigned int)__shfl_xor((int)Wp[kb][m], 32);
      }
    // ---- PV: O^T[d][q] += V^T * P^T ----
#pragma unroll
    for (int ks = 0; ks < 4; ++ks) {
      const int kb = ks >> 1, s = ks & 1;
      const unsigned int w0 = hi ? Xp[kb][4 * s + 2] : Wp[kb][4 * s + 0];
      const unsigned int w1 = hi ? Xp[kb][4 * s + 3] : Wp[kb][4 * s + 1];
      const unsigned int w2 = hi ? Wp[kb][4 * s + 2] : Xp[kb][4 * s + 0];
      const unsigned int w3 = hi ? Wp[kb][4 * s + 3] : Xp[kb][4 * s + 1];
      union { uint4 u; bf16x8 v; } pu;
      pu.u = make_uint4(w0, w1, w2, w3);
      const bf16x8 pf = pu.v;
#pragma unroll
      for (int nb = 0; nb < 8; ++nb) {
        const int ch = nb * 32 + lq;
        const int voff = (ch * 128 + ks * 32 + hi * 16) ^ ((ch & 7) << 4);
        const bf16x8 vf = *(const bf16x8*)(Vc + voff);
        oacc[nb] = __builtin_amdgcn_mfma_f32_32x32x16_bf16(vf, pf,
                                                           oacc[nb], 0, 0, 0);
      }
    }
    __syncthreads();  // drains vmcnt (prefetch) + all waves done with cur
  }
  // ---- epilogue: normalize, store fp32 O[row][ch] ----
  const float inv = 1.f / lrow;
  float* orow = o + ((size_t)b * Np + q0 + w * 32 + lq) * Cc;
#pragma unroll
  for (int nb = 0; nb < 8; ++nb)
#pragma unroll
    for (int g = 0; g < 4; ++g) {
      float4 val;
      val.x = oacc[nb][4 * g + 0] * inv;
      val.y = oacc[nb][4 * g + 1] * inv;
      val.z = oacc[nb][4 * g + 2] * inv;
      val.w = oacc[nb][4 * g + 3] * inv;
      *(float4*)(orow + nb * 32 + 8 * g + hi * 4) = val;
    }
}

// ---------------- final projection + residual ----------------
__global__ __launch_bounds__(256) void final_gemm_k(
    const float* __restrict__ h2, const float* __restrict__ Wf,
    const float* __restrict__ bf, const float* __restrict__ x,
    float* __restrict__ out) {
  __shared__ float As[16][68];
  __shared__ float Bs[16][68];
  const int m0 = blockIdx.x * 64;
  const int n0 = blockIdx.y * 64;
  const int t = threadIdx.x;
  const int tm = t >> 4, tn = t & 15;
  float ac[4][4] = {};
  for (int k0 = 0; k0 < Cc; k0 += 16) {
    __syncthreads();
    {
      const int m = t >> 2, kk4 = (t & 3) * 4;
      const float4 a = *(const float4*)(h2 + (size_t)(m0 + m) * Cc + k0 + kk4);
      As[kk4 + 0][m] = a.x;
      As[kk4 + 1][m] = a.y;
      As[kk4 + 2][m] = a.z;
      As[kk4 + 3][m] = a.w;
    }
    {
      const int kk = t >> 4, n4 = (t & 15) * 4;
      *(float4*)&Bs[kk][n4] =
          *(const float4*)(Wf + (size_t)(k0 + kk) * Cc + n0 + n4);
    }
    __syncthreads();
#pragma unroll
    for (int kk = 0; kk < 16; ++kk) {
      const float4 a4 = *(const float4*)&As[kk][tm * 4];
      const float4 b4 = *(const float4*)&Bs[kk][tn * 4];
      const float a[4] = {a4.x, a4.y, a4.z, a4.w};
      const float bb[4] = {b4.x, b4.y, b4.z, b4.w};
#pragma unroll
      for (int i = 0; i < 4; ++i)
#pragma unroll
        for (int j = 0; j < 4; ++j) ac[i][j] += a[i] * bb[j];
    }
  }
  const float4 bia = *(const float4*)(bf + n0 + tn * 4);
#pragma unroll
  for (int i = 0; i < 4; ++i) {
    const size_t r = (size_t)(m0 + tm * 4 + i) * Cc + n0 + tn * 4;
    const float4 xv = *(const float4*)(x + r);
    float4 oo;
    oo.x = (xv.x + ac[i][0] + bia.x) * kRsqrt2;
    oo.y = (xv.y + ac[i][1] + bia.y) * kRsqrt2;
    oo.z = (xv.z + ac[i][2] + bia.z) * kRsqrt2;
    oo.w = (xv.w + ac[i][3] + bia.w) * kRsqrt2;
    *(float4*)(out + r) = oo;
  }
}

extern "C" void kernel_launch(void* const* d_in, const int* in_sizes, int n_in,
                              void* d_out, int out_size, void* d_ws,
                              size_t ws_size, hipStream_t stream) {
  const float* x = (const float*)d_in[0];
  const float* gs = (const float*)d_in[1];
  const float* gb = (const float*)d_in[2];
  const float* Wq = (const float*)d_in[3];
  const float* bq = (const float*)d_in[4];
  const float* Wk = (const float*)d_in[5];
  const float* bk = (const float*)d_in[6];
  const float* Wv = (const float*)d_in[7];
  const float* bv = (const float*)d_in[8];
  const float* Wf = (const float*)d_in[9];
  const float* bf = (const float*)d_in[10];
  float* out = (float*)d_out;

  // workspace: h fp32 (reused for attn out) | q bf16 | k_sw bf16 | v_sw bf16 | st
  float* h = (float*)d_ws;
  u16* qb = (u16*)(h + (size_t)kRows * Cc);
  u16* kb = qb + (size_t)kRows * Cc;
  u16* vtt = kb + (size_t)kRows * Cc;
  float* st = (float*)(vtt + (size_t)kRows * Cc);

  gn_stats_k<<<dim3(Bn * 32), dim3(256), 0, stream>>>(x, st);
  gn_apply_k<<<dim3(1024), dim3(256), 0, stream>>>(x, st, gs, gb, h);
  qkv_gemm_k<<<dim3(kRows / 64, Cc / 64), dim3(256), 0, stream>>>(
      h, Wq, bq, Wk, bk, Wv, bv, qb, kb, vtt);
  attn_mfma_k<<<dim3(256), dim3(256), 0, stream>>>(qb, kb, vtt, h);
  final_gemm_k<<<dim3(kRows / 64, Cc / 64), dim3(256), 0, stream>>>(h, Wf, bf,
                                                                    x, out);
}